// Round 1
// 511.757 us; speedup vs baseline: 1.0351x; 1.0351x over previous
//
#include <hip/hip_runtime.h>

// Problem constants (fixed by reference)
#define R_   3
#define N_   50000
#define E_   400000
#define IN_  128
#define HID_ 64
#define C_   40
#define H_   3
#define NEG_SLOPE 0.2f
#define LOG2E 1.4426950408889634f

#define SCAN_CHUNK 1024
#define NCH  49      // ceil(N_/1024)
#define NCH2 64      // padded stride

typedef _Float16 half_t;
typedef _Float16 f16x8 __attribute__((ext_vector_type(8)));
typedef _Float16 f16x4 __attribute__((ext_vector_type(4)));
typedef float float4v __attribute__((ext_vector_type(4)));

template <int V> struct vecT;
template <> struct vecT<4> { typedef f16x4 type; };
template <> struct vecT<8> { typedef f16x8 type; };

// ---------------- utility ----------------
__global__ void zero_kernel(float* __restrict__ p, size_t n) {
    size_t i = (size_t)blockIdx.x * blockDim.x + threadIdx.x;
    if (i < n) p[i] = 0.f;
}

// float -> half, vectorized x4 (n must be divisible by 4)
__global__ void cast_f2h_kernel(const float* __restrict__ in, half_t* __restrict__ outp, int n4) {
    int i = blockIdx.x * 256 + threadIdx.x;
    if (i < n4) {
        float4 v = ((const float4*)in)[i];
        f16x4 h;
        h[0] = (half_t)v.x; h[1] = (half_t)v.y;
        h[2] = (half_t)v.z; h[3] = (half_t)v.w;
        ((f16x4*)outp)[i] = h;
    }
}

// W: [R][K][Nc] fp32 -> Wt: [R][Nc][K] fp16 (tiny matrices)
__global__ void transcast_kernel(const float* __restrict__ W, half_t* __restrict__ Wt,
                                 int K, int Nc) {
    int idx = blockIdx.x * 256 + threadIdx.x;
    int total = R_ * K * Nc;
    if (idx < total) {
        int r = idx / (K * Nc);
        int rem = idx - r * K * Nc;
        int n = rem / K;
        int k = rem - n * K;
        Wt[idx] = (half_t)W[((size_t)r * K + k) * Nc + n];
    }
}

// ---------------- CSR build ----------------
__global__ void hist_kernel(const int* __restrict__ dst, int* __restrict__ deg) {
    int idx = blockIdx.x * 256 + threadIdx.x;
    if (idx < R_ * E_) {
        int r = idx / E_;
        atomicAdd(&deg[r * N_ + dst[idx]], 1);
    }
}

__global__ void scanA_kernel(const int* __restrict__ deg, int* __restrict__ bsum) {
    int r = blockIdx.y, ch = blockIdx.x, tid = threadIdx.x;
    int base = ch * SCAN_CHUNK + tid * 4;
    int s = 0;
    for (int j = 0; j < 4; ++j) {
        int i = base + j;
        if (i < N_) s += deg[r * N_ + i];
    }
    __shared__ int red[256];
    red[tid] = s; __syncthreads();
    for (int off = 128; off; off >>= 1) {
        if (tid < off) red[tid] += red[tid + off];
        __syncthreads();
    }
    if (tid == 0) bsum[r * NCH2 + ch] = red[0];
}

// scanB v2: one wave per relation, shfl_up scan over the 49 chunk sums
// (replaces 3-thread serial loop with ~100 dependent global round-trips)
__global__ void scanB_kernel(int* __restrict__ bsum) {
    int w = threadIdx.x >> 6;      // relation
    int l = threadIdx.x & 63;
    if (w < R_) {
        int v = (l < NCH) ? bsum[w * NCH2 + l] : 0;
        int s = v;
        #pragma unroll
        for (int off = 1; off < 64; off <<= 1) {
            int t = __shfl_up(s, off);
            if (l >= off) s += t;
        }
        if (l < NCH) bsum[w * NCH2 + l] = s - v;   // exclusive
    }
}

__global__ void scanC_kernel(const int* __restrict__ deg, const int* __restrict__ bsum,
                             int* __restrict__ rowptr, int* __restrict__ cursor) {
    int r = blockIdx.y, ch = blockIdx.x, tid = threadIdx.x;
    int base = ch * SCAN_CHUNK + tid * 4;
    int v[4]; int s = 0;
    for (int j = 0; j < 4; ++j) {
        int i = base + j;
        v[j] = (i < N_) ? deg[r * N_ + i] : 0;
        s += v[j];
    }
    __shared__ int buf[256];
    buf[tid] = s; __syncthreads();
    for (int off = 1; off < 256; off <<= 1) {
        int t2 = (tid >= off) ? buf[tid - off] : 0;
        __syncthreads();
        buf[tid] += t2;
        __syncthreads();
    }
    int excl = buf[tid] - s + bsum[r * NCH2 + ch];
    int run = excl;
    for (int j = 0; j < 4; ++j) {
        int i = base + j;
        if (i < N_) {
            rowptr[r * (N_ + 1) + i] = run;
            cursor[r * N_ + i] = run;
            run += v[j];
        }
    }
    if (ch == 0 && tid == 0) rowptr[r * (N_ + 1) + N_] = E_;
}

// fill v2: store src*3 ("s3") so agg's el index is s3+h (add) and the z
// row offset is s3*Dd (single shift for Dd=64) — kills a v_mul per gather.
__global__ void fill_kernel(const int* __restrict__ src, const int* __restrict__ dst,
                            int* __restrict__ cursor, int* __restrict__ csr_src) {
    int idx = blockIdx.x * 256 + threadIdx.x;
    if (idx < R_ * E_) {
        int r = idx / E_;
        int pos = atomicAdd(&cursor[r * N_ + dst[idx]], 1);
        csr_src[(size_t)r * E_ + pos] = src[idx] * 3;
    }
}

// ---------------- MFMA GEMM: Z[r] = A @ Bt[r]^T (row stride = Nc) ----------------
// FUSE: layer-1 attention-logit fusion. Each blockIdx.y 64-col tile == one head
// (HID=64), and the wave holds the fp16-rounded z fragment in registers, so
// el/er = z . al/ar is 32 fma + a 16-lane butterfly — saves the attn2 pass
// that re-read the whole 57.6MB z buffer. Logits pre-scaled by LOG2E so the
// agg inner loop uses raw v_exp_f32.
template <int K, bool FUSE>
__global__ __launch_bounds__(256) void mfma_gemm_kernel(
        const half_t* __restrict__ A, const half_t* __restrict__ Bt,
        half_t* __restrict__ Z, int M, int Nc,
        const float* __restrict__ al, const float* __restrict__ ar,
        float* __restrict__ el, float* __restrict__ er) {
    int r = blockIdx.z;
    int wave = threadIdx.x >> 6, lane = threadIdx.x & 63;
    int lrow = lane & 15, lq = lane >> 4;
    int rowA = blockIdx.x * 64 + wave * 16 + lrow;
    int col0 = blockIdx.y * 64;
    const half_t* Btr = Bt + (size_t)r * Nc * K;
    const half_t* aP = A + (size_t)rowA * K + lq * 8;
    bool arow_ok = (rowA < M);
    f16x8 zv8 = {};
    float4v acc[4] = {};
    #pragma unroll
    for (int k0 = 0; k0 < K; k0 += 32) {
        f16x8 af = arow_ok ? *(const f16x8*)(aP + k0) : zv8;
        #pragma unroll
        for (int ct = 0; ct < 4; ++ct) {
            int col = col0 + ct * 16 + lrow;
            f16x8 bf = (col < Nc) ? *(const f16x8*)(Btr + (size_t)col * K + lq * 8 + k0) : zv8;
            acc[ct] = __builtin_amdgcn_mfma_f32_16x16x32_f16(af, bf, acc[ct], 0, 0, 0);
        }
    }
    half_t* Zr = Z + (size_t)r * N_ * Nc;
    int rbase = blockIdx.x * 64 + wave * 16 + lq * 4;
    float elv[4] = {}, erv[4] = {};
    const float* alp;
    const float* arp;
    if constexpr (FUSE) {
        alp = al + ((size_t)r * H_ + blockIdx.y) * 64;
        arp = ar + ((size_t)r * H_ + blockIdx.y) * 64;
    }
    #pragma unroll
    for (int ct = 0; ct < 4; ++ct) {
        int col = col0 + ct * 16 + lrow;
        if (col >= Nc) continue;
        float wa = 0.f, wb = 0.f;
        if constexpr (FUSE) { wa = alp[ct * 16 + lrow]; wb = arp[ct * 16 + lrow]; }
        #pragma unroll
        for (int g = 0; g < 4; ++g) {
            int row = rbase + g;
            half_t zh = (half_t)acc[ct][g];
            if (row < M) Zr[(size_t)row * Nc + col] = zh;
            if constexpr (FUSE) {
                float zf = (float)zh;
                elv[g] = fmaf(zf, wa, elv[g]);
                erv[g] = fmaf(zf, wb, erv[g]);
            }
        }
    }
    if constexpr (FUSE) {
        #pragma unroll
        for (int g = 0; g < 4; ++g) {
            #pragma unroll
            for (int m = 1; m < 16; m <<= 1) {
                elv[g] += __shfl_xor(elv[g], m);
                erv[g] += __shfl_xor(erv[g], m);
            }
        }
        if (lrow == 0) {
            #pragma unroll
            for (int g = 0; g < 4; ++g) {
                int row = rbase + g;
                if (row < M) {
                    size_t o = ((size_t)r * N_ + row) * H_ + blockIdx.y;
                    el[o] = elv[g] * LOG2E;
                    er[o] = erv[g] * LOG2E;
                }
            }
        }
    }
}

// ---------------- attention logits (layer 2 only): one THREAD per (r,n,h) ----
// Writes logits pre-scaled by LOG2E for the exp2-based agg loop.
template <int Dd>
__global__ __launch_bounds__(256) void attn2_kernel(
        const half_t* __restrict__ z, const float* __restrict__ al,
        const float* __restrict__ ar, float* __restrict__ el,
        float* __restrict__ er) {
    int t = blockIdx.x * 256 + threadIdx.x;
    if (t >= R_ * N_ * H_) return;
    int rn = t / H_, h = t - rn * H_;
    int r = rn / N_;
    const half_t* zrow = z + (size_t)rn * (3 * Dd) + h * Dd;
    const float* alp = al + (r * H_ + h) * Dd;
    const float* arp = ar + (r * H_ + h) * Dd;
    float p0 = 0.f, p1 = 0.f, q0 = 0.f, q1 = 0.f;
    #pragma unroll
    for (int c = 0; c < Dd / 8; ++c) {
        f16x8 zv = *(const f16x8*)(zrow + c * 8);
        #pragma unroll
        for (int j = 0; j < 8; j += 2) {
            float za = (float)zv[j], zb = (float)zv[j + 1];
            p0 += za * alp[c * 8 + j];
            p1 += zb * alp[c * 8 + j + 1];
            q0 += za * arp[c * 8 + j];
            q1 += zb * arp[c * 8 + j + 1];
        }
    }
    el[t] = (p0 + p1) * LOG2E;
    er[t] = (q0 + q1) * LOG2E;
}

// ---------------- fused softmax + gather + aggregate (v13) ----
// agg12 structure (one wave per node, 3 relations interleaved, split-wave,
// no-max softmax, fp16 packed accum) with two VALU-overhead cuts:
//  - csr holds src*3: el index = s3+h (add), z half-offset = s3*Dd (shift
//    for Dd=64) — removes the s*ROWH multiply per gather.
//  - logits arrive pre-scaled by LOG2E: exp is a bare v_exp_f32.
// Overflow-safe: c <= exp(~8) ~ 3e3, |a| <= ~1e4 << 65504.
template <int Dd, int VEC, bool RELU, typename OutT>
__global__ __launch_bounds__(256) void agg13_kernel(
        const int* __restrict__ rowptr, const int* __restrict__ csr_src,
        const half_t* __restrict__ z, const float* __restrict__ el,
        const float* __restrict__ er, const float* __restrict__ bias,
        OutT* __restrict__ out, float scale) {
    constexpr int ROWH = 3 * Dd;        // halves per z row
    constexpr int LPE  = ROWH / VEC;    // sub-lanes per edge (24 / 30)
    constexpr int PH   = Dd / VEC;      // sub-lanes per head (8 / 10)
    using fv = typename vecT<VEC>::type;
    int n = blockIdx.x * 4 + (threadIdx.x >> 6);
    int lane = threadIdx.x & 63;
    if (n >= N_) return;
    int hf = lane >> 5;                 // half-wave index
    int sub = lane & 31;
    bool act = sub < LPE;
    int hl = act ? sub / PH : 0;
    int dl = act ? sub - hl * PH : 0;
    int zoff = VEC * sub;
    // ---- prologue: all relations' bounds + erv (independent loads) ----
    int ii[R_], ee[R_];
    float ervv[R_];
    #pragma unroll
    for (int r = 0; r < R_; ++r) {
        ii[r] = rowptr[r * (N_ + 1) + n];
        ee[r] = rowptr[r * (N_ + 1) + n + 1];
        ervv[r] = er[((size_t)r * N_ + n) * H_ + hl];
    }
    fv ah[R_] = {};                     // fp16 packed accumulators
    float ll[R_] = {};
    // ---- merged loop: 4 edges per relation per iteration ----
    while (ii[0] < ee[0] || ii[1] < ee[1] || ii[2] < ee[2]) {
        fv zA[R_], zB[R_];
        float xA[R_], xB[R_];
        bool okA[R_], okB[R_];
        #pragma unroll
        for (int r = 0; r < R_; ++r) {
            const int* cs = csr_src + (size_t)r * E_;
            const half_t* zr = z + (size_t)r * N_ * ROWH;
            const float* elr = el + (size_t)r * N_ * H_;
            int eA = ii[r] + hf, eB = ii[r] + 2 + hf;
            okA[r] = eA < ee[r];
            okB[r] = eB < ee[r];
            int sA = cs[okA[r] ? eA : 0];       // s3 = src*3
            int sB = cs[okB[r] ? eB : 0];
            xA[r] = elr[sA + hl] + ervv[r];
            xB[r] = elr[sB + hl] + ervv[r];
            zA[r] = {}; zB[r] = {};
            if (act) {
                zA[r] = *(const fv*)(zr + (size_t)sA * Dd + zoff);
                zB[r] = *(const fv*)(zr + (size_t)sB * Dd + zoff);
            }
        }
        #pragma unroll
        for (int r = 0; r < R_; ++r) {
            float xa = xA[r]; xa = fmaxf(xa, NEG_SLOPE * xa);
            float xb = xB[r]; xb = fmaxf(xb, NEG_SLOPE * xb);
            float cA = okA[r] ? __builtin_amdgcn_exp2f(xa) : 0.f;
            float cB = okB[r] ? __builtin_amdgcn_exp2f(xb) : 0.f;
            ll[r] += cA + cB;
            half_t hA = (half_t)cA, hB = (half_t)cB;
            fv vA, vB;
            #pragma unroll
            for (int v = 0; v < VEC; ++v) { vA[v] = hA; vB[v] = hB; }
            ah[r] += vA * zA[r] + vB * zB[r];   // v_pk_fma_f16
        }
        #pragma unroll
        for (int r = 0; r < R_; ++r) ii[r] += 4;
    }
    // ---- epilogue: convert to fp32 once, then cross-half combines ----
    float aa[R_][VEC];
    #pragma unroll
    for (int r = 0; r < R_; ++r)
        #pragma unroll
        for (int v = 0; v < VEC; ++v) aa[r][v] = (float)ah[r][v];
    #pragma unroll
    for (int r = 0; r < R_; ++r) {
        #pragma unroll
        for (int v = 0; v < VEC; ++v) aa[r][v] += __shfl(aa[r][v], lane ^ 32);
        ll[r] += __shfl(ll[r], lane ^ 32);
    }
    float vacc[VEC] = {};
    #pragma unroll
    for (int r = 0; r < R_; ++r) {
        float li = (ll[r] > 0.f) ? 1.f / ll[r] : 0.f;
        const float* br = bias + r * ROWH + hl * Dd + VEC * dl;
        #pragma unroll
        for (int v = 0; v < VEC; ++v) {
            float t = aa[r][v] * li + br[v];
            if (RELU) t = fmaxf(t, 0.f);
            vacc[v] += t;
        }
    }
    // ---- final head-sum (cyclic within half, exact 3-term) ----
    int base = lane & 32;
    int p1 = sub + PH;     if (p1 >= LPE) p1 -= LPE;
    int p2 = sub + 2 * PH; if (p2 >= LPE) p2 -= LPE;
    #pragma unroll
    for (int v = 0; v < VEC; ++v)
        vacc[v] += __shfl(vacc[v], base + p1) + __shfl(vacc[v], base + p2);
    // ---- redistribute: lane j holds output col j ----
    int srcl = lane / VEC;
    int cm = lane & (VEC - 1);
    float tv[VEC];
    #pragma unroll
    for (int v = 0; v < VEC; ++v) tv[v] = __shfl(vacc[v], srcl);
    float outv = tv[0];
    #pragma unroll
    for (int v = 1; v < VEC; ++v) outv = (cm == v) ? tv[v] : outv;
    if (lane < Dd) out[(size_t)n * Dd + lane] = (OutT)(outv * scale);
}

// ---------------- launch ----------------
static inline size_t align256(size_t x) { return (x + 255) & ~(size_t)255; }

extern "C" void kernel_launch(void* const* d_in, const int* in_sizes, int n_in,
                              void* d_out, int out_size, void* d_ws, size_t ws_size,
                              hipStream_t stream) {
    const float* feat = (const float*)d_in[0];
    const int*   src  = (const int*)d_in[1];
    const int*   dst  = (const int*)d_in[2];
    const float* W1   = (const float*)d_in[3];
    const float* al1  = (const float*)d_in[4];
    const float* ar1  = (const float*)d_in[5];
    const float* b1   = (const float*)d_in[6];
    const float* W2   = (const float*)d_in[7];
    const float* al2  = (const float*)d_in[8];
    const float* ar2  = (const float*)d_in[9];
    const float* b2   = (const float*)d_in[10];
    float* out = (float*)d_out;

    // workspace carve
    char* ws = (char*)d_ws;
    size_t off = 0;
    half_t* zbuf = (half_t*)(ws + off); off += align256((size_t)R_ * N_ * (3 * HID_) * 2);
    half_t* featH = (half_t*)(ws + off); off += align256((size_t)N_ * IN_ * 2);
    half_t* h1h  = (half_t*)(ws + off); off += align256((size_t)N_ * HID_ * 2);
    half_t* W1t  = (half_t*)(ws + off); off += align256((size_t)R_ * (H_ * HID_) * IN_ * 2);
    half_t* W2t  = (half_t*)(ws + off); off += align256((size_t)R_ * (H_ * C_) * HID_ * 2);
    float* el   = (float*)(ws + off); off += align256((size_t)R_ * N_ * H_ * 4);
    float* er   = (float*)(ws + off); off += align256((size_t)R_ * N_ * H_ * 4);
    int* deg    = (int*)(ws + off);   off += align256((size_t)R_ * N_ * 4);
    int* rowptr = (int*)(ws + off);   off += align256((size_t)R_ * (N_ + 1) * 4);
    int* cursor = (int*)(ws + off);   off += align256((size_t)R_ * N_ * 4);
    int* bsum   = (int*)(ws + off);   off += align256((size_t)R_ * NCH2 * 4);
    int* csr    = (int*)(ws + off);   off += align256((size_t)R_ * E_ * 4);
    (void)ws_size; (void)n_in; (void)in_sizes; (void)out_size;

    const int EDGE_BLOCKS = (R_ * E_ + 255) / 256;     // 4688
    const int ROW_TILES = (N_ + 63) / 64;              // 782
    const int NODE_BLOCKS = (R_ * N_ + 255) / 256;     // 586
    const int NODE_WAVES = (N_ + 3) / 4;               // 12500
    const int ATTN_BLOCKS = (R_ * N_ * H_ + 255) / 256;// 1758

    // ---- input casts / weight transposes ----
    cast_f2h_kernel<<<(N_ * IN_ / 4 + 255) / 256, 256, 0, stream>>>(feat, featH, N_ * IN_ / 4);
    transcast_kernel<<<(R_ * IN_ * (H_ * HID_) + 255) / 256, 256, 0, stream>>>(W1, W1t, IN_, H_ * HID_);
    transcast_kernel<<<(R_ * HID_ * (H_ * C_) + 255) / 256, 256, 0, stream>>>(W2, W2t, HID_, H_ * C_);

    // ---- CSR build (shared by both layers) ----
    zero_kernel<<<NODE_BLOCKS, 256, 0, stream>>>((float*)deg, (size_t)R_ * N_);
    hist_kernel<<<EDGE_BLOCKS, 256, 0, stream>>>(dst, deg);
    scanA_kernel<<<dim3(NCH, R_), 256, 0, stream>>>(deg, bsum);
    scanB_kernel<<<1, 192, 0, stream>>>(bsum);
    scanC_kernel<<<dim3(NCH, R_), 256, 0, stream>>>(deg, bsum, rowptr, cursor);
    fill_kernel<<<EDGE_BLOCKS, 256, 0, stream>>>(src, dst, cursor, csr);

    // ---- layer 1: IN -> H*HID, relu; gemm fuses el/er; agg writes h1h ----
    mfma_gemm_kernel<IN_, true><<<dim3(ROW_TILES, 3, R_), 256, 0, stream>>>(
        featH, W1t, zbuf, N_, H_ * HID_, al1, ar1, el, er);
    agg13_kernel<HID_, 8, true, half_t><<<NODE_WAVES, 256, 0, stream>>>(
        rowptr, csr, zbuf, el, er, b1, h1h, 1.f / (H_ * R_));

    // ---- layer 2: HID -> H*C, no relu; agg writes d_out (fp32) directly ----
    mfma_gemm_kernel<HID_, false><<<dim3(ROW_TILES, 2, R_), 256, 0, stream>>>(
        h1h, W2t, zbuf, N_, H_ * C_, nullptr, nullptr, nullptr, nullptr);
    attn2_kernel<C_><<<ATTN_BLOCKS, 256, 0, stream>>>(zbuf, al2, ar2, el, er);
    agg13_kernel<C_, 4, false, float><<<NODE_WAVES, 256, 0, stream>>>(
        rowptr, csr, zbuf, el, er, b2, out, 1.f / (H_ * R_));
}

// Round 2
// 449.891 us; speedup vs baseline: 1.1775x; 1.1375x over previous
//
#include <hip/hip_runtime.h>

// Problem constants (fixed by reference)
#define R_   3
#define N_   50000
#define E_   400000
#define IN_  128
#define HID_ 64
#define C_   40
#define H_   3
#define NEG_SLOPE 0.2f
#define LOG2E 1.4426950408889634f

#define SCAN_CHUNK 1024
#define NCH  49      // ceil(N_/1024)
#define NCH2 64      // padded stride

#define MPAD 50048   // 782*64 rows (grid-rounded)
#define NRT  3128    // MPAD/16 fragment row-tiles

typedef _Float16 half_t;
typedef _Float16 f16x8 __attribute__((ext_vector_type(8)));
typedef _Float16 f16x4 __attribute__((ext_vector_type(4)));
typedef float float4v __attribute__((ext_vector_type(4)));

template <int V> struct vecT;
template <> struct vecT<4> { typedef f16x4 type; };
template <> struct vecT<8> { typedef f16x8 type; };

// ---------------- utility ----------------
__global__ void zero_kernel(float* __restrict__ p, size_t n) {
    size_t i = (size_t)blockIdx.x * blockDim.x + threadIdx.x;
    if (i < n) p[i] = 0.f;
}

// ---- feat fp32 [N][IN] -> fragment-tiled fp16 A' ----
// A'[(rowtile*KB + kb)*64 + lane] is f16x8; lane supplies
// row = rowtile*16 + (lane&15), k = kb*32 + (lane>>4)*8 (+j).
// Matches mfma_f32_16x16x32_f16 A-operand layout. Pad rows >= N_ are zero.
__global__ void cast_tiled_kernel(const float* __restrict__ feat, half_t* __restrict__ At) {
    int idx = blockIdx.x * 256 + threadIdx.x;          // f16x8 index
    const int TOT = NRT * 4 * 64;                      // KB=4 for IN=128
    if (idx >= TOT) return;
    int lane = idx & 63;
    int kb = (idx >> 6) & 3;
    int rowtile = idx >> 8;
    int row = rowtile * 16 + (lane & 15);
    int k = kb * 32 + (lane >> 4) * 8;
    f16x8 h = {};
    if (row < N_) {
        const float* p = feat + (size_t)row * IN_ + k;
        float4 a = ((const float4*)p)[0];
        float4 b = ((const float4*)p)[1];
        h[0] = (half_t)a.x; h[1] = (half_t)a.y; h[2] = (half_t)a.z; h[3] = (half_t)a.w;
        h[4] = (half_t)b.x; h[5] = (half_t)b.y; h[6] = (half_t)b.z; h[7] = (half_t)b.w;
    }
    ((f16x8*)At)[idx] = h;                             // fully coalesced write
}

// ---- W fp32 [R][K][Nc] -> fragment-ordered fp16 B' ----
// B'[(((r*NY + y)*KB + kb)*4 + ct)*64 + lane] f16x8; lane supplies
// col = y*64 + ct*16 + (lane&15), k = kb*32 + (lane>>4)*8 (+j).
// Cols >= Nc padded with zeros so GEMM loads are unguarded.
template <int K, int NY>
__global__ void bprep_kernel(const float* __restrict__ W, half_t* __restrict__ Bf, int Nc) {
    constexpr int KB = K / 32;
    int idx = blockIdx.x * 256 + threadIdx.x;
    const int TOT = R_ * NY * KB * 4 * 64;
    if (idx >= TOT) return;
    int lane = idx & 63;
    int ct = (idx >> 6) & 3;
    int t = idx >> 8;                 // (r*NY + y)*KB + kb
    int kb = t % KB; t /= KB;
    int y = t % NY;  int r = t / NY;
    int col = y * 64 + ct * 16 + (lane & 15);
    int k0 = kb * 32 + (lane >> 4) * 8;
    f16x8 h = {};
    if (col < Nc) {
        #pragma unroll
        for (int j = 0; j < 8; ++j)
            h[j] = (half_t)W[((size_t)r * K + k0 + j) * Nc + col];
    }
    ((f16x8*)Bf)[idx] = h;
}

// ---------------- CSR build ----------------
__global__ void hist_kernel(const int* __restrict__ dst, int* __restrict__ deg) {
    int idx = blockIdx.x * 256 + threadIdx.x;
    if (idx < R_ * E_) {
        int r = idx / E_;
        atomicAdd(&deg[r * N_ + dst[idx]], 1);
    }
}

__global__ void scanA_kernel(const int* __restrict__ deg, int* __restrict__ bsum) {
    int r = blockIdx.y, ch = blockIdx.x, tid = threadIdx.x;
    int base = ch * SCAN_CHUNK + tid * 4;
    int s = 0;
    for (int j = 0; j < 4; ++j) {
        int i = base + j;
        if (i < N_) s += deg[r * N_ + i];
    }
    __shared__ int red[256];
    red[tid] = s; __syncthreads();
    for (int off = 128; off; off >>= 1) {
        if (tid < off) red[tid] += red[tid + off];
        __syncthreads();
    }
    if (tid == 0) bsum[r * NCH2 + ch] = red[0];
}

// scanB: one wave per relation, shfl_up scan over the 49 chunk sums
__global__ void scanB_kernel(int* __restrict__ bsum) {
    int w = threadIdx.x >> 6;      // relation
    int l = threadIdx.x & 63;
    if (w < R_) {
        int v = (l < NCH) ? bsum[w * NCH2 + l] : 0;
        int s = v;
        #pragma unroll
        for (int off = 1; off < 64; off <<= 1) {
            int t = __shfl_up(s, off);
            if (l >= off) s += t;
        }
        if (l < NCH) bsum[w * NCH2 + l] = s - v;   // exclusive
    }
}

__global__ void scanC_kernel(const int* __restrict__ deg, const int* __restrict__ bsum,
                             int* __restrict__ rowptr, int* __restrict__ cursor) {
    int r = blockIdx.y, ch = blockIdx.x, tid = threadIdx.x;
    int base = ch * SCAN_CHUNK + tid * 4;
    int v[4]; int s = 0;
    for (int j = 0; j < 4; ++j) {
        int i = base + j;
        v[j] = (i < N_) ? deg[r * N_ + i] : 0;
        s += v[j];
    }
    __shared__ int buf[256];
    buf[tid] = s; __syncthreads();
    for (int off = 1; off < 256; off <<= 1) {
        int t2 = (tid >= off) ? buf[tid - off] : 0;
        __syncthreads();
        buf[tid] += t2;
        __syncthreads();
    }
    int excl = buf[tid] - s + bsum[r * NCH2 + ch];
    int run = excl;
    for (int j = 0; j < 4; ++j) {
        int i = base + j;
        if (i < N_) {
            rowptr[r * (N_ + 1) + i] = run;
            cursor[r * N_ + i] = run;
            run += v[j];
        }
    }
    if (ch == 0 && tid == 0) rowptr[r * (N_ + 1) + N_] = E_;
}

// fill: store src*3 ("s3") so agg's el index is s3+h (add) and the z
// row offset is s3*Dd (single shift for Dd=64).
__global__ void fill_kernel(const int* __restrict__ src, const int* __restrict__ dst,
                            int* __restrict__ cursor, int* __restrict__ csr_src) {
    int idx = blockIdx.x * 256 + threadIdx.x;
    if (idx < R_ * E_) {
        int r = idx / E_;
        int pos = atomicAdd(&cursor[r * N_ + dst[idx]], 1);
        csr_src[(size_t)r * E_ + pos] = src[idx] * 3;
    }
}

// ---------------- MFMA GEMM v3: fragment-ordered operands ----------------
// Both A' and B' are pre-tiled in MFMA fragment order, so EVERY operand load
// is a fully-coalesced 1KiB wave load (v2 was 16-way row-scatter per load:
// ~54 cyc/VMEM instr measured -> TA-bound at 92us, MfmaUtil 3%).
// FUSE (layer 1): each y tile == one head; el/er computed from the register
// fragment + 16-lane butterfly; logits pre-scaled by LOG2E.
template <int K, int NY, bool FUSE>
__global__ __launch_bounds__(256) void mfma_gemm3_kernel(
        const half_t* __restrict__ At, const half_t* __restrict__ Bf,
        half_t* __restrict__ Z, int Nc,
        const float* __restrict__ al, const float* __restrict__ ar,
        float* __restrict__ el, float* __restrict__ er) {
    constexpr int KB = K / 32;
    int r = blockIdx.z, y = blockIdx.y;
    int wave = threadIdx.x >> 6, lane = threadIdx.x & 63;
    int rowtile = blockIdx.x * 4 + wave;
    const f16x8* Ap = (const f16x8*)At + (size_t)rowtile * KB * 64 + lane;
    const f16x8* Bp = (const f16x8*)Bf + (size_t)(r * NY + y) * KB * 4 * 64 + lane;
    float4v acc[4] = {};
    #pragma unroll
    for (int kb = 0; kb < KB; ++kb) {
        f16x8 af = Ap[kb * 64];
        #pragma unroll
        for (int ct = 0; ct < 4; ++ct) {
            f16x8 bf = Bp[(kb * 4 + ct) * 64];
            acc[ct] = __builtin_amdgcn_mfma_f32_16x16x32_f16(af, bf, acc[ct], 0, 0, 0);
        }
    }
    int lrow = lane & 15, lq = lane >> 4;
    half_t* Zr = Z + (size_t)r * N_ * Nc;
    int rbase = rowtile * 16 + lq * 4;
    int col0 = y * 64;
    float elv[4] = {}, erv[4] = {};
    const float* alp;
    const float* arp;
    if constexpr (FUSE) {
        alp = al + ((size_t)r * H_ + y) * 64;
        arp = ar + ((size_t)r * H_ + y) * 64;
    }
    #pragma unroll
    for (int ct = 0; ct < 4; ++ct) {
        int col = col0 + ct * 16 + lrow;
        if (col >= Nc) continue;
        float wa = 0.f, wb = 0.f;
        if constexpr (FUSE) { wa = alp[ct * 16 + lrow]; wb = arp[ct * 16 + lrow]; }
        #pragma unroll
        for (int g = 0; g < 4; ++g) {
            int row = rbase + g;
            half_t zh = (half_t)acc[ct][g];
            if (row < N_) Zr[(size_t)row * Nc + col] = zh;
            if constexpr (FUSE) {
                float zf = (float)zh;
                elv[g] = fmaf(zf, wa, elv[g]);
                erv[g] = fmaf(zf, wb, erv[g]);
            }
        }
    }
    if constexpr (FUSE) {
        #pragma unroll
        for (int g = 0; g < 4; ++g) {
            #pragma unroll
            for (int m = 1; m < 16; m <<= 1) {
                elv[g] += __shfl_xor(elv[g], m);
                erv[g] += __shfl_xor(erv[g], m);
            }
        }
        if (lrow == 0) {
            #pragma unroll
            for (int g = 0; g < 4; ++g) {
                int row = rbase + g;
                if (row < N_) {
                    size_t o = ((size_t)r * N_ + row) * H_ + y;
                    el[o] = elv[g] * LOG2E;
                    er[o] = erv[g] * LOG2E;
                }
            }
        }
    }
}

// ---------------- attention logits (layer 2 only) ----------------
template <int Dd>
__global__ __launch_bounds__(256) void attn2_kernel(
        const half_t* __restrict__ z, const float* __restrict__ al,
        const float* __restrict__ ar, float* __restrict__ el,
        float* __restrict__ er) {
    int t = blockIdx.x * 256 + threadIdx.x;
    if (t >= R_ * N_ * H_) return;
    int rn = t / H_, h = t - rn * H_;
    int r = rn / N_;
    const half_t* zrow = z + (size_t)rn * (3 * Dd) + h * Dd;
    const float* alp = al + (r * H_ + h) * Dd;
    const float* arp = ar + (r * H_ + h) * Dd;
    float p0 = 0.f, p1 = 0.f, q0 = 0.f, q1 = 0.f;
    #pragma unroll
    for (int c = 0; c < Dd / 8; ++c) {
        f16x8 zv = *(const f16x8*)(zrow + c * 8);
        #pragma unroll
        for (int j = 0; j < 8; j += 2) {
            float za = (float)zv[j], zb = (float)zv[j + 1];
            p0 += za * alp[c * 8 + j];
            p1 += zb * alp[c * 8 + j + 1];
            q0 += za * arp[c * 8 + j];
            q1 += zb * arp[c * 8 + j + 1];
        }
    }
    el[t] = (p0 + p1) * LOG2E;
    er[t] = (q0 + q1) * LOG2E;
}

// ---------------- fused softmax + gather + aggregate (v14) ----------------
// agg13 structure; TILED=true additionally writes the output in the
// fragment-tiled A' layout (for the next layer's GEMM) at the same cost as
// the flat store: one 2B element per lane at a computed offset.
template <int Dd, int VEC, bool RELU, typename OutT, bool TILED>
__global__ __launch_bounds__(256) void agg14_kernel(
        const int* __restrict__ rowptr, const int* __restrict__ csr_src,
        const half_t* __restrict__ z, const float* __restrict__ el,
        const float* __restrict__ er, const float* __restrict__ bias,
        OutT* __restrict__ out, float scale) {
    constexpr int ROWH = 3 * Dd;        // halves per z row
    constexpr int LPE  = ROWH / VEC;    // sub-lanes per edge (24 / 30)
    constexpr int PH   = Dd / VEC;      // sub-lanes per head (8 / 10)
    using fv = typename vecT<VEC>::type;
    int n = blockIdx.x * 4 + (threadIdx.x >> 6);
    int lane = threadIdx.x & 63;
    if (n >= N_) return;
    int hf = lane >> 5;                 // half-wave index
    int sub = lane & 31;
    bool act = sub < LPE;
    int hl = act ? sub / PH : 0;
    int dl = act ? sub - hl * PH : 0;
    int zoff = VEC * sub;
    int ii[R_], ee[R_];
    float ervv[R_];
    #pragma unroll
    for (int r = 0; r < R_; ++r) {
        ii[r] = rowptr[r * (N_ + 1) + n];
        ee[r] = rowptr[r * (N_ + 1) + n + 1];
        ervv[r] = er[((size_t)r * N_ + n) * H_ + hl];
    }
    fv ah[R_] = {};                     // fp16 packed accumulators
    float ll[R_] = {};
    while (ii[0] < ee[0] || ii[1] < ee[1] || ii[2] < ee[2]) {
        fv zA[R_], zB[R_];
        float xA[R_], xB[R_];
        bool okA[R_], okB[R_];
        #pragma unroll
        for (int r = 0; r < R_; ++r) {
            const int* cs = csr_src + (size_t)r * E_;
            const half_t* zr = z + (size_t)r * N_ * ROWH;
            const float* elr = el + (size_t)r * N_ * H_;
            int eA = ii[r] + hf, eB = ii[r] + 2 + hf;
            okA[r] = eA < ee[r];
            okB[r] = eB < ee[r];
            int sA = cs[okA[r] ? eA : 0];       // s3 = src*3
            int sB = cs[okB[r] ? eB : 0];
            xA[r] = elr[sA + hl] + ervv[r];
            xB[r] = elr[sB + hl] + ervv[r];
            zA[r] = {}; zB[r] = {};
            if (act) {
                zA[r] = *(const fv*)(zr + (size_t)sA * Dd + zoff);
                zB[r] = *(const fv*)(zr + (size_t)sB * Dd + zoff);
            }
        }
        #pragma unroll
        for (int r = 0; r < R_; ++r) {
            float xa = xA[r]; xa = fmaxf(xa, NEG_SLOPE * xa);
            float xb = xB[r]; xb = fmaxf(xb, NEG_SLOPE * xb);
            float cA = okA[r] ? __builtin_amdgcn_exp2f(xa) : 0.f;
            float cB = okB[r] ? __builtin_amdgcn_exp2f(xb) : 0.f;
            ll[r] += cA + cB;
            half_t hA = (half_t)cA, hB = (half_t)cB;
            fv vA, vB;
            #pragma unroll
            for (int v = 0; v < VEC; ++v) { vA[v] = hA; vB[v] = hB; }
            ah[r] += vA * zA[r] + vB * zB[r];   // v_pk_fma_f16
        }
        #pragma unroll
        for (int r = 0; r < R_; ++r) ii[r] += 4;
    }
    float aa[R_][VEC];
    #pragma unroll
    for (int r = 0; r < R_; ++r)
        #pragma unroll
        for (int v = 0; v < VEC; ++v) aa[r][v] = (float)ah[r][v];
    #pragma unroll
    for (int r = 0; r < R_; ++r) {
        #pragma unroll
        for (int v = 0; v < VEC; ++v) aa[r][v] += __shfl(aa[r][v], lane ^ 32);
        ll[r] += __shfl(ll[r], lane ^ 32);
    }
    float vacc[VEC] = {};
    #pragma unroll
    for (int r = 0; r < R_; ++r) {
        float li = (ll[r] > 0.f) ? 1.f / ll[r] : 0.f;
        const float* br = bias + r * ROWH + hl * Dd + VEC * dl;
        #pragma unroll
        for (int v = 0; v < VEC; ++v) {
            float t = aa[r][v] * li + br[v];
            if (RELU) t = fmaxf(t, 0.f);
            vacc[v] += t;
        }
    }
    int base = lane & 32;
    int p1 = sub + PH;     if (p1 >= LPE) p1 -= LPE;
    int p2 = sub + 2 * PH; if (p2 >= LPE) p2 -= LPE;
    #pragma unroll
    for (int v = 0; v < VEC; ++v)
        vacc[v] += __shfl(vacc[v], base + p1) + __shfl(vacc[v], base + p2);
    int srcl = lane / VEC;
    int cm = lane & (VEC - 1);
    float tv[VEC];
    #pragma unroll
    for (int v = 0; v < VEC; ++v) tv[v] = __shfl(vacc[v], srcl);
    float outv = tv[0];
    #pragma unroll
    for (int v = 1; v < VEC; ++v) outv = (cm == v) ? tv[v] : outv;
    if constexpr (TILED) {
        // lane == k (0..63); write fragment-tiled A' for next layer (KB=2)
        int rowtile = n >> 4;
        int kb = lane >> 5;
        int fl = (n & 15) + ((lane >> 3) & 3) * 16;
        int elo = lane & 7;
        size_t ho = (((size_t)rowtile * 2 + kb) * 64 + fl) * 8 + elo;
        ((half_t*)out)[ho] = (half_t)(outv * scale);
    } else {
        if (lane < Dd) out[(size_t)n * Dd + lane] = (OutT)(outv * scale);
    }
}

// ---------------- launch ----------------
static inline size_t align256(size_t x) { return (x + 255) & ~(size_t)255; }

extern "C" void kernel_launch(void* const* d_in, const int* in_sizes, int n_in,
                              void* d_out, int out_size, void* d_ws, size_t ws_size,
                              hipStream_t stream) {
    const float* feat = (const float*)d_in[0];
    const int*   src  = (const int*)d_in[1];
    const int*   dst  = (const int*)d_in[2];
    const float* W1   = (const float*)d_in[3];
    const float* al1  = (const float*)d_in[4];
    const float* ar1  = (const float*)d_in[5];
    const float* b1   = (const float*)d_in[6];
    const float* W2   = (const float*)d_in[7];
    const float* al2  = (const float*)d_in[8];
    const float* ar2  = (const float*)d_in[9];
    const float* b2   = (const float*)d_in[10];
    float* out = (float*)d_out;

    // workspace carve
    char* ws = (char*)d_ws;
    size_t off = 0;
    half_t* zbuf  = (half_t*)(ws + off); off += align256((size_t)R_ * N_ * (3 * HID_) * 2);
    half_t* featT = (half_t*)(ws + off); off += align256((size_t)NRT * 4 * 64 * 8 * 2);
    half_t* h1T   = (half_t*)(ws + off); off += align256((size_t)NRT * 2 * 64 * 8 * 2);
    half_t* B1f   = (half_t*)(ws + off); off += align256((size_t)R_ * 3 * 4 * 4 * 64 * 8 * 2);
    half_t* B2f   = (half_t*)(ws + off); off += align256((size_t)R_ * 2 * 2 * 4 * 64 * 8 * 2);
    float* el   = (float*)(ws + off); off += align256((size_t)R_ * N_ * H_ * 4);
    float* er   = (float*)(ws + off); off += align256((size_t)R_ * N_ * H_ * 4);
    int* deg    = (int*)(ws + off);   off += align256((size_t)R_ * N_ * 4);
    int* rowptr = (int*)(ws + off);   off += align256((size_t)R_ * (N_ + 1) * 4);
    int* cursor = (int*)(ws + off);   off += align256((size_t)R_ * N_ * 4);
    int* bsum   = (int*)(ws + off);   off += align256((size_t)R_ * NCH2 * 4);
    int* csr    = (int*)(ws + off);   off += align256((size_t)R_ * E_ * 4);
    (void)ws_size; (void)n_in; (void)in_sizes; (void)out_size;

    const int EDGE_BLOCKS = (R_ * E_ + 255) / 256;     // 4688
    const int ROW_TILES = (N_ + 63) / 64;              // 782
    const int NODE_BLOCKS = (R_ * N_ + 255) / 256;     // 586
    const int NODE_WAVES = (N_ + 3) / 4;               // 12500
    const int ATTN_BLOCKS = (R_ * N_ * H_ + 255) / 256;// 1758

    // ---- operand prep: tiled A' for layer 1, fragment-ordered B' ----
    cast_tiled_kernel<<<(NRT * 4 * 64 + 255) / 256, 256, 0, stream>>>(feat, featT);
    bprep_kernel<IN_, 3><<<(R_ * 3 * 4 * 4 * 64 + 255) / 256, 256, 0, stream>>>(W1, B1f, H_ * HID_);
    bprep_kernel<HID_, 2><<<(R_ * 2 * 2 * 4 * 64 + 255) / 256, 256, 0, stream>>>(W2, B2f, H_ * C_);
    // zero h1T's pad row-tiles (rows 50000..50047): 3 tiles * 2 kb * 512 halves
    zero_kernel<<<7, 256, 0, stream>>>((float*)(h1T + (size_t)3125 * 2 * 512), 1536);

    // ---- CSR build (shared by both layers) ----
    zero_kernel<<<NODE_BLOCKS, 256, 0, stream>>>((float*)deg, (size_t)R_ * N_);
    hist_kernel<<<EDGE_BLOCKS, 256, 0, stream>>>(dst, deg);
    scanA_kernel<<<dim3(NCH, R_), 256, 0, stream>>>(deg, bsum);
    scanB_kernel<<<1, 192, 0, stream>>>(bsum);
    scanC_kernel<<<dim3(NCH, R_), 256, 0, stream>>>(deg, bsum, rowptr, cursor);
    fill_kernel<<<EDGE_BLOCKS, 256, 0, stream>>>(src, dst, cursor, csr);

    // ---- layer 1: IN -> H*HID, relu; gemm fuses el/er; agg writes h1T tiled ----
    mfma_gemm3_kernel<IN_, 3, true><<<dim3(ROW_TILES, 3, R_), 256, 0, stream>>>(
        featT, B1f, zbuf, H_ * HID_, al1, ar1, el, er);
    agg14_kernel<HID_, 8, true, half_t, true><<<NODE_WAVES, 256, 0, stream>>>(
        rowptr, csr, zbuf, el, er, b1, h1T, 1.f / (H_ * R_));

    // ---- layer 2: HID -> H*C, no relu; agg writes d_out (fp32) ----
    mfma_gemm3_kernel<HID_, 2, false><<<dim3(ROW_TILES, 2, R_), 256, 0, stream>>>(
        h1T, B2f, zbuf, H_ * C_, nullptr, nullptr, nullptr, nullptr);
    attn2_kernel<C_><<<ATTN_BLOCKS, 256, 0, stream>>>(zbuf, al2, ar2, el, er);
    agg14_kernel<C_, 4, false, float, false><<<NODE_WAVES, 256, 0, stream>>>(
        rowptr, csr, zbuf, el, er, b2, out, 1.f / (H_ * R_));
}